// Round 4
// baseline (277.665 us; speedup 1.0000x reference)
//
#include <hip/hip_runtime.h>

#define D 128
#define DH 64      // uints per feature row (2 bf16 per uint)
#define RCAP 64    // per-row slab capacity (Poisson mean 16, P(>=64) ~ 1e-19)
#define TS 68      // LDS tile row stride in uints (272 B: 16B-aligned, bank-spread)

typedef float f32x4 __attribute__((ext_vector_type(4)));
typedef short s16x8 __attribute__((ext_vector_type(8)));

static __device__ __forceinline__ unsigned short f2bf(float f) {
    unsigned u = __float_as_uint(f);
    u += 0x7FFF + ((u >> 16) & 1);   // RNE
    return (unsigned short)(u >> 16);
}
static __device__ __forceinline__ float bflo(unsigned u) { return __uint_as_float(u << 16); }
static __device__ __forceinline__ float bfhi(unsigned u) { return __uint_as_float(u & 0xFFFF0000u); }
static __device__ __forceinline__ float bf2f(short v) {
    return __uint_as_float(((unsigned)(unsigned short)v) << 16);
}

// ---- fused setup: [0,eb) xpack | [eb,eb+16) prepw | [eb+16,..) zero rowcnt+stats ----
__global__ __launch_bounds__(256)
void k_setup(const float* __restrict__ x, unsigned* __restrict__ xh, int total4,
             const float* __restrict__ W1, const float* __restrict__ W2,
             unsigned short* __restrict__ Wsw1, unsigned short* __restrict__ Wsw2,
             int* __restrict__ rowcnt, float* __restrict__ stats, int eb, int npad) {
    int bid = blockIdx.x, t = threadIdx.x;
    if (bid < eb) {
        int i = bid * 256 + t;
        if (i < total4) {
            float4 v = ((const float4*)x)[i];
            uint2 o;
            o.x = (unsigned)f2bf(v.x) | ((unsigned)f2bf(v.y) << 16);
            o.y = (unsigned)f2bf(v.z) | ((unsigned)f2bf(v.w) << 16);
            ((uint2*)xh)[i] = o;
        }
    } else if (bid < eb + 16) {
        int gidx = (bid - eb) * 256 + t;   // 0..4095
        const float* W = (gidx < 2048) ? W1 : W2;
        unsigned short* Wsw = (gidx < 2048) ? Wsw1 : Wsw2;
        int idx = gidx & 2047;
        int lane = idx & 63, nt = (idx >> 6) & 7, kt = idx >> 9;
        int k0 = kt * 32 + (lane >> 4) * 8;
        int n = nt * 16 + (lane & 15);
        unsigned short* dst = &Wsw[(size_t)((kt * 8 + nt) * 64 + lane) * 8];
#pragma unroll
        for (int j = 0; j < 8; ++j) dst[j] = f2bf(W[(k0 + j) * D + n]);
    } else {
        int z = bid - eb - 16;
        int idx = z * 256 + t;
        if (idx < npad) rowcnt[idx] = 0;
        if (z == 0) { stats[t] = 0.f; stats[256 + t] = 0.f; }   // 4*D = 512 floats
    }
}

// ---- direct per-row slab scatter: one global atomic per edge, no sort needed ----
__global__ __launch_bounds__(256)
void k_scatter(const int* __restrict__ rows, const int* __restrict__ cols,
               const float* __restrict__ vals, int* __restrict__ rowcnt,
               uint2* __restrict__ rowslab, int E) {
    int stride = gridDim.x * blockDim.x;
    for (int e = blockIdx.x * blockDim.x + threadIdx.x; e < E; e += stride) {
        int r = rows[e];
        int p = atomicAdd(&rowcnt[r], 1);
        if (p < RCAP)
            rowslab[(size_t)r * RCAP + p] =
                make_uint2((unsigned)cols[e], __float_as_uint(vals[e]));
    }
}

// ---- fused gather + layer-1 MFMA GEMM + batch-stat partials ----
// 256 thr = 4 waves; block owns 64 rows: gather them into an LDS tile, then GEMM1.
__global__ __launch_bounds__(256)
void k_gathergemm1(const uint2* __restrict__ rowslab, const int* __restrict__ rowcnt,
                   const unsigned* __restrict__ xh, const float* __restrict__ eps,
                   const unsigned short* __restrict__ Wsw, const float* __restrict__ bias,
                   unsigned short* __restrict__ Hout, float* __restrict__ stats, int N) {
    __shared__ unsigned tile[64 * TS];   // packed bf16x2 agg tile, 17 KB
    __shared__ float redS[4 * D];
    __shared__ float redQ[4 * D];
    int tid = threadIdx.x, lane = tid & 63, w = tid >> 6;
    int row0 = blockIdx.x * 64;
    float s = 1.0f + eps[0];

    // ---- gather phase: wave w handles rows w, w+4, ... (16 rows each) ----
    for (int rl = w; rl < 64; rl += 4) {
        int grow = row0 + rl;
        if (grow >= N) { tile[rl * TS + lane] = 0; continue; }
        unsigned u = xh[(size_t)grow * DH + lane];
        float ax = s * bflo(u), ay = s * bfhi(u);
        int cnt = rowcnt[grow];
        if (cnt > RCAP) cnt = RCAP;
        const uint2* base = &rowslab[(size_t)grow * RCAP];
        int i = 0;
        for (; i + 8 <= cnt; i += 8) {
            uint2 ed[8];
            unsigned uu[8];
#pragma unroll
            for (int j = 0; j < 8; ++j) ed[j] = base[i + j];
#pragma unroll
            for (int j = 0; j < 8; ++j) uu[j] = xh[(size_t)ed[j].x * DH + lane];
#pragma unroll
            for (int j = 0; j < 8; ++j) {
                float v = __uint_as_float(ed[j].y);
                ax += v * bflo(uu[j]);
                ay += v * bfhi(uu[j]);
            }
        }
        for (; i < cnt; ++i) {
            uint2 ed = base[i];
            unsigned uu = xh[(size_t)ed.x * DH + lane];
            float v = __uint_as_float(ed.y);
            ax += v * bflo(uu);
            ay += v * bfhi(uu);
        }
        tile[rl * TS + lane] = (unsigned)f2bf(ax) | ((unsigned)f2bf(ay) << 16);
    }
    __syncthreads();

    // ---- GEMM1 phase: wave w owns tile rows w*16..w*16+15 ----
    int m = lane & 15, quad = lane >> 4;
    int wrow0 = row0 + w * 16;

    f32x4 acc[8];
#pragma unroll
    for (int nt = 0; nt < 8; ++nt) acc[nt] = (f32x4){0.f, 0.f, 0.f, 0.f};

    const s16x8* wp = (const s16x8*)Wsw;
#pragma unroll
    for (int kt = 0; kt < 4; ++kt) {
        s16x8 a = *(const s16x8*)&tile[(w * 16 + m) * TS + kt * 16 + quad * 4];
#pragma unroll
        for (int nt = 0; nt < 8; ++nt) {
            s16x8 b = wp[(kt * 8 + nt) * 64 + lane];
            acc[nt] = __builtin_amdgcn_mfma_f32_16x16x32_bf16(a, b, acc[nt], 0, 0, 0);
        }
    }

#pragma unroll
    for (int nt = 0; nt < 8; ++nt) {
        float bv = bias[nt * 16 + m];
        float ss = 0.f, q = 0.f;
#pragma unroll
        for (int r = 0; r < 4; ++r) {
            int row = wrow0 + quad * 4 + r;
            float h = acc[nt][r] + bv;
            if (row < N) {
                Hout[(size_t)row * D + nt * 16 + m] = f2bf(h);
                ss += h; q += h * h;
            }
        }
        ss += __shfl_xor(ss, 16, 64); ss += __shfl_xor(ss, 32, 64);
        q += __shfl_xor(q, 16, 64);   q += __shfl_xor(q, 32, 64);
        if (quad == 0) {
            redS[w * D + nt * 16 + m] = ss;
            redQ[w * D + nt * 16 + m] = q;
        }
    }
    __syncthreads();
    if (tid < D) {
        float ts = redS[tid] + redS[D + tid] + redS[2 * D + tid] + redS[3 * D + tid];
        float tq = redQ[tid] + redQ[D + tid] + redQ[2 * D + tid] + redQ[3 * D + tid];
        atomicAdd(&stats[tid], ts);
        atomicAdd(&stats[D + tid], tq);
    }
}

// ---- layer-2 GEMM with BN1+swish fused into the A-load; stats2 partials ----
__global__ __launch_bounds__(256)
void k_gemm2f(const unsigned short* __restrict__ H1, const unsigned short* __restrict__ Wsw,
              const float* __restrict__ bias, const float* __restrict__ stats1,
              const float* __restrict__ g1, const float* __restrict__ be1, float invN,
              unsigned short* __restrict__ Hout, float* __restrict__ stats2, int N) {
    __shared__ float redS[4 * D];
    __shared__ float redQ[4 * D];
    __shared__ float sa[D], sb[D];
    int tid = threadIdx.x, lane = tid & 63, w = tid >> 6;
    if (tid < D) {
        float mean = stats1[tid] * invN;
        float var = fmaxf(stats1[D + tid] * invN - mean * mean, 0.f);
        float a = g1[tid] * rsqrtf(var + 1e-5f);
        sa[tid] = a;
        sb[tid] = be1[tid] - mean * a;
    }
    __syncthreads();

    int row0 = blockIdx.x * 64 + w * 16;
    int m = lane & 15, quad = lane >> 4;

    f32x4 acc[8];
#pragma unroll
    for (int nt = 0; nt < 8; ++nt) acc[nt] = (f32x4){0.f, 0.f, 0.f, 0.f};

    int arow = row0 + m;
    bool avalid = arow < N;
    const s16x8* wp = (const s16x8*)Wsw;
    s16x8 az = {0, 0, 0, 0, 0, 0, 0, 0};
#pragma unroll
    for (int kt = 0; kt < 4; ++kt) {
        s16x8 a = az;
        if (avalid) {
            s16x8 raw = *(const s16x8*)&H1[(size_t)arow * D + kt * 32 + quad * 8];
#pragma unroll
            for (int j = 0; j < 8; ++j) {
                int k = kt * 32 + quad * 8 + j;
                float dd = bf2f(raw[j]) * sa[k] + sb[k];
                float o = dd / (1.f + __expf(-dd));
                a[j] = (short)f2bf(o);
            }
        }
#pragma unroll
        for (int nt = 0; nt < 8; ++nt) {
            s16x8 b = wp[(kt * 8 + nt) * 64 + lane];
            acc[nt] = __builtin_amdgcn_mfma_f32_16x16x32_bf16(a, b, acc[nt], 0, 0, 0);
        }
    }

#pragma unroll
    for (int nt = 0; nt < 8; ++nt) {
        float bv = bias[nt * 16 + m];
        float s = 0.f, q = 0.f;
#pragma unroll
        for (int r = 0; r < 4; ++r) {
            int row = row0 + quad * 4 + r;
            float h = acc[nt][r] + bv;
            if (row < N) {
                Hout[(size_t)row * D + nt * 16 + m] = f2bf(h);
                s += h; q += h * h;
            }
        }
        s += __shfl_xor(s, 16, 64); s += __shfl_xor(s, 32, 64);
        q += __shfl_xor(q, 16, 64); q += __shfl_xor(q, 32, 64);
        if (quad == 0) {
            redS[w * D + nt * 16 + m] = s;
            redQ[w * D + nt * 16 + m] = q;
        }
    }
    __syncthreads();
    if (tid < D) {
        float ts = redS[tid] + redS[D + tid] + redS[2 * D + tid] + redS[3 * D + tid];
        float tq = redQ[tid] + redQ[D + tid] + redQ[2 * D + tid] + redQ[3 * D + tid];
        atomicAdd(&stats2[tid], ts);
        atomicAdd(&stats2[D + tid], tq);
    }
}

// ---- final BN + swish -> fp32 out (finalize fused from raw sums) ----
__global__ void k_bnswish(const unsigned* __restrict__ inh, float* __restrict__ outp,
                          const float* __restrict__ stats, const float* __restrict__ g,
                          const float* __restrict__ be, float invN, int total4) {
    __shared__ float sa[D], sb[D];
    int j = threadIdx.x;
    if (j < D) {
        float mean = stats[j] * invN;
        float var = fmaxf(stats[D + j] * invN - mean * mean, 0.f);
        float a = g[j] * rsqrtf(var + 1e-5f);
        sa[j] = a;
        sb[j] = be[j] - mean * a;
    }
    __syncthreads();
    int i = blockIdx.x * blockDim.x + threadIdx.x;
    if (i >= total4) return;
    uint2 u = ((const uint2*)inh)[i];
    int c = (i * 4) & (D - 1);
    float d0 = bflo(u.x) * sa[c + 0] + sb[c + 0];
    float d1 = bfhi(u.x) * sa[c + 1] + sb[c + 1];
    float d2 = bflo(u.y) * sa[c + 2] + sb[c + 2];
    float d3 = bfhi(u.y) * sa[c + 3] + sb[c + 3];
    float o0 = d0 / (1.f + __expf(-d0));
    float o1 = d1 / (1.f + __expf(-d1));
    float o2 = d2 / (1.f + __expf(-d2));
    float o3 = d3 / (1.f + __expf(-d3));
    ((float4*)outp)[i] = make_float4(o0, o1, o2, o3);
}

extern "C" void kernel_launch(void* const* d_in, const int* in_sizes, int n_in,
                              void* d_out, int out_size, void* d_ws, size_t ws_size,
                              hipStream_t stream) {
    const float* x    = (const float*)d_in[0];
    const float* vals = (const float*)d_in[1];
    const float* W1   = (const float*)d_in[2];
    const float* b1   = (const float*)d_in[3];
    const float* g1   = (const float*)d_in[4];
    const float* be1  = (const float*)d_in[5];
    const float* W2   = (const float*)d_in[6];
    const float* b2   = (const float*)d_in[7];
    const float* g2   = (const float*)d_in[8];
    const float* be2  = (const float*)d_in[9];
    const float* eps  = (const float*)d_in[10];
    const int*  rows  = (const int*)d_in[11];
    const int*  cols  = (const int*)d_in[12];
    float* out = (float*)d_out;

    int N = in_sizes[0] / D;
    int E = in_sizes[1];
    int gblk = (N + 63) / 64;            // 782 tiles
    int npad = gblk * 64;                // 50048

    // ---- workspace layout ----
    char* p = (char*)d_ws;
    float* stats = (float*)p;              p += 4 * D * sizeof(float);   // stats1 | stats2
    int* rowcnt = (int*)p;                 p += (size_t)npad * sizeof(int);
    p = (char*)(((uintptr_t)p + 15) & ~(uintptr_t)15);
    unsigned short* Wsw1 = (unsigned short*)p; p += (size_t)D * D * 2;
    unsigned short* Wsw2 = (unsigned short*)p; p += (size_t)D * D * 2;
    p = (char*)(((uintptr_t)p + 15) & ~(uintptr_t)15);
    uint2* rowslab = (uint2*)p;            p += (size_t)npad * RCAP * sizeof(uint2); // 25.6 MB
    unsigned* xh = (unsigned*)p;           p += (size_t)N * DH * sizeof(unsigned);
    unsigned* h1 = (unsigned*)p;           p += (size_t)N * DH * sizeof(unsigned);
    unsigned* h2 = (unsigned*)p;           /* N*DH uints */

    float* stats1 = stats;
    float* stats2 = stats + 2 * D;

    int total4 = N * D / 4;
    int eb = (total4 + 255) / 256;
    int zb = (npad + 255) / 256;
    float invN = 1.0f / (float)N;

    // 1. fused setup: xpack | prepw | zero(rowcnt,stats)
    k_setup<<<eb + 16 + zb, 256, 0, stream>>>(x, xh, total4, W1, W2, Wsw1, Wsw2,
                                              rowcnt, stats, eb, npad);
    // 2. direct per-row slab scatter (sort eliminated entirely)
    k_scatter<<<1024, 256, 0, stream>>>(rows, cols, vals, rowcnt, rowslab, E);
    // 3. fused gather + layer-1 GEMM (+stats1); agg never touches global
    k_gathergemm1<<<gblk, 256, 0, stream>>>(rowslab, rowcnt, xh, eps, Wsw1, b1,
                                            (unsigned short*)h1, stats1, N);
    // 4. layer-2 GEMM with BN1+swish fused on A; (+stats2)
    k_gemm2f<<<gblk, 256, 0, stream>>>((const unsigned short*)h1, Wsw2, b2,
                                       stats1, g1, be1, invN,
                                       (unsigned short*)h2, stats2, N);
    // 5. final BN+swish -> fp32 out
    k_bnswish<<<eb, 256, 0, stream>>>(h2, out, stats2, g2, be2, invN, total4);
}

// Round 5
// 266.408 us; speedup vs baseline: 1.0423x; 1.0423x over previous
//
#include <hip/hip_runtime.h>

#define D 128
#define DH 64      // uints per feature row (2 bf16 per uint)
#define RCAP 64    // per-row slab capacity (Poisson mean 16, P(>=64) ~ 1e-19)
#define GR 32      // rows per gather block (grid ~1563 -> 4 blocks/CU sustained)

typedef float f32x4 __attribute__((ext_vector_type(4)));
typedef short s16x8 __attribute__((ext_vector_type(8)));

static __device__ __forceinline__ unsigned short f2bf(float f) {
    unsigned u = __float_as_uint(f);
    u += 0x7FFF + ((u >> 16) & 1);   // RNE
    return (unsigned short)(u >> 16);
}
static __device__ __forceinline__ float bflo(unsigned u) { return __uint_as_float(u << 16); }
static __device__ __forceinline__ float bfhi(unsigned u) { return __uint_as_float(u & 0xFFFF0000u); }
static __device__ __forceinline__ float bf2f(short v) {
    return __uint_as_float(((unsigned)(unsigned short)v) << 16);
}

// ---- fused setup: [0,eb) xpack | [eb,eb+16) prepw | [eb+16,..) zero rowcnt+stats ----
__global__ __launch_bounds__(256)
void k_setup(const float* __restrict__ x, unsigned* __restrict__ xh, int total4,
             const float* __restrict__ W1, const float* __restrict__ W2,
             unsigned short* __restrict__ Wsw1, unsigned short* __restrict__ Wsw2,
             int* __restrict__ rowcnt, float* __restrict__ stats, int eb, int npad) {
    int bid = blockIdx.x, t = threadIdx.x;
    if (bid < eb) {
        int i = bid * 256 + t;
        if (i < total4) {
            float4 v = ((const float4*)x)[i];
            uint2 o;
            o.x = (unsigned)f2bf(v.x) | ((unsigned)f2bf(v.y) << 16);
            o.y = (unsigned)f2bf(v.z) | ((unsigned)f2bf(v.w) << 16);
            ((uint2*)xh)[i] = o;
        }
    } else if (bid < eb + 16) {
        int gidx = (bid - eb) * 256 + t;   // 0..4095
        const float* W = (gidx < 2048) ? W1 : W2;
        unsigned short* Wsw = (gidx < 2048) ? Wsw1 : Wsw2;
        int idx = gidx & 2047;
        int lane = idx & 63, nt = (idx >> 6) & 7, kt = idx >> 9;
        int k0 = kt * 32 + (lane >> 4) * 8;
        int n = nt * 16 + (lane & 15);
        unsigned short* dst = &Wsw[(size_t)((kt * 8 + nt) * 64 + lane) * 8];
#pragma unroll
        for (int j = 0; j < 8; ++j) dst[j] = f2bf(W[(k0 + j) * D + n]);
    } else {
        int z = bid - eb - 16;
        int idx = z * 256 + t;
        if (idx < npad) rowcnt[idx] = 0;
        if (z == 0) { stats[t] = 0.f; stats[256 + t] = 0.f; }   // 4*D = 512 floats
    }
}

// ---- direct per-row slab scatter: one global atomic per edge, no sort needed ----
__global__ __launch_bounds__(256)
void k_scatter(const int* __restrict__ rows, const int* __restrict__ cols,
               const float* __restrict__ vals, int* __restrict__ rowcnt,
               uint2* __restrict__ rowslab, int E) {
    int stride = gridDim.x * blockDim.x;
    for (int e = blockIdx.x * blockDim.x + threadIdx.x; e < E; e += stride) {
        int r = rows[e];
        int p = atomicAdd(&rowcnt[r], 1);
        if (p < RCAP)
            rowslab[(size_t)r * RCAP + p] =
                make_uint2((unsigned)cols[e], __float_as_uint(vals[e]));
    }
}

// ---- gather: slabs LDS-staged (bulk coalesced), 8 waves, 32 rows/block ----
__global__ __launch_bounds__(512, 8)
void k_gather(const uint2* __restrict__ rowslab, const int* __restrict__ rowcnt,
              const unsigned* __restrict__ xh, const float* __restrict__ eps,
              unsigned* __restrict__ aggh, int N) {
    __shared__ uint2 sl[GR * RCAP];   // 16 KB staged edge slabs
    __shared__ int scnt[GR];
    int b = blockIdx.x, t = threadIdx.x;
    int row0 = b * GR;

    // bulk coalesced staging: 16 KB per block as uint4 (2 slots/op)
    {
        const uint4* src = (const uint4*)&rowslab[(size_t)row0 * RCAP];
        uint4* dst = (uint4*)sl;
        for (int i = t; i < GR * RCAP / 2; i += 512) dst[i] = src[i];
    }
    if (t < GR) {
        int g = row0 + t;
        int c = (g < N) ? rowcnt[g] : 0;
        scnt[t] = (c > RCAP) ? RCAP : c;
    }
    __syncthreads();

    int lane = t & 63, w = t >> 6;   // 8 waves, 4 rows each
    float s = 1.0f + eps[0];
    for (int rl = w; rl < GR; rl += 8) {
        int grow = row0 + rl;
        if (grow >= N) break;
        unsigned u = xh[(size_t)grow * DH + lane];
        float ax = s * bflo(u), ay = s * bfhi(u);
        int cnt = scnt[rl];
        const uint2* base = &sl[rl * RCAP];
        int i = 0;
        for (; i + 8 <= cnt; i += 8) {
            uint2 ed[8];
            unsigned uu[8];
#pragma unroll
            for (int j = 0; j < 8; ++j) ed[j] = base[i + j];
#pragma unroll
            for (int j = 0; j < 8; ++j) uu[j] = xh[(size_t)ed[j].x * DH + lane];
#pragma unroll
            for (int j = 0; j < 8; ++j) {
                float v = __uint_as_float(ed[j].y);
                ax += v * bflo(uu[j]);
                ay += v * bfhi(uu[j]);
            }
        }
        for (; i < cnt; ++i) {
            uint2 ed = base[i];
            unsigned uu = xh[(size_t)ed.x * DH + lane];
            float v = __uint_as_float(ed.y);
            ax += v * bflo(uu);
            ay += v * bfhi(uu);
        }
        aggh[(size_t)grow * DH + lane] = (unsigned)f2bf(ax) | ((unsigned)f2bf(ay) << 16);
    }
}

// ---- layer-1 MFMA GEMM + fused batch-stat partials ----
__global__ __launch_bounds__(256)
void k_gemm(const unsigned short* __restrict__ A, const unsigned short* __restrict__ Wsw,
            const float* __restrict__ bias, unsigned short* __restrict__ Hout,
            float* __restrict__ stats, int N) {
    __shared__ float redS[4 * D];
    __shared__ float redQ[4 * D];
    int tid = threadIdx.x, lane = tid & 63, w = tid >> 6;
    int row0 = blockIdx.x * 64 + w * 16;
    int m = lane & 15, quad = lane >> 4;

    f32x4 acc[8];
#pragma unroll
    for (int nt = 0; nt < 8; ++nt) acc[nt] = (f32x4){0.f, 0.f, 0.f, 0.f};

    int arow = row0 + m;
    bool avalid = arow < N;
    const s16x8* wp = (const s16x8*)Wsw;
    s16x8 az = {0, 0, 0, 0, 0, 0, 0, 0};
#pragma unroll
    for (int kt = 0; kt < 4; ++kt) {
        s16x8 a = avalid ? *(const s16x8*)&A[(size_t)arow * D + kt * 32 + quad * 8] : az;
#pragma unroll
        for (int nt = 0; nt < 8; ++nt) {
            s16x8 b = wp[(kt * 8 + nt) * 64 + lane];
            acc[nt] = __builtin_amdgcn_mfma_f32_16x16x32_bf16(a, b, acc[nt], 0, 0, 0);
        }
    }

#pragma unroll
    for (int nt = 0; nt < 8; ++nt) {
        float bv = bias[nt * 16 + m];
        float s = 0.f, q = 0.f;
#pragma unroll
        for (int r = 0; r < 4; ++r) {
            int row = row0 + quad * 4 + r;
            float h = acc[nt][r] + bv;
            if (row < N) {
                Hout[(size_t)row * D + nt * 16 + m] = f2bf(h);
                s += h; q += h * h;
            }
        }
        s += __shfl_xor(s, 16, 64); s += __shfl_xor(s, 32, 64);
        q += __shfl_xor(q, 16, 64); q += __shfl_xor(q, 32, 64);
        if (quad == 0) {
            redS[w * D + nt * 16 + m] = s;
            redQ[w * D + nt * 16 + m] = q;
        }
    }
    __syncthreads();
    if (tid < D) {
        float ts = redS[tid] + redS[D + tid] + redS[2 * D + tid] + redS[3 * D + tid];
        float tq = redQ[tid] + redQ[D + tid] + redQ[2 * D + tid] + redQ[3 * D + tid];
        atomicAdd(&stats[tid], ts);
        atomicAdd(&stats[D + tid], tq);
    }
}

// ---- layer-2 GEMM with BN1+swish fused into the A-load; stats2 partials ----
__global__ __launch_bounds__(256)
void k_gemm2f(const unsigned short* __restrict__ H1, const unsigned short* __restrict__ Wsw,
              const float* __restrict__ bias, const float* __restrict__ stats1,
              const float* __restrict__ g1, const float* __restrict__ be1, float invN,
              unsigned short* __restrict__ Hout, float* __restrict__ stats2, int N) {
    __shared__ float redS[4 * D];
    __shared__ float redQ[4 * D];
    __shared__ float sa[D], sb[D];
    int tid = threadIdx.x, lane = tid & 63, w = tid >> 6;
    if (tid < D) {
        float mean = stats1[tid] * invN;
        float var = fmaxf(stats1[D + tid] * invN - mean * mean, 0.f);
        float a = g1[tid] * rsqrtf(var + 1e-5f);
        sa[tid] = a;
        sb[tid] = be1[tid] - mean * a;
    }
    __syncthreads();

    int row0 = blockIdx.x * 64 + w * 16;
    int m = lane & 15, quad = lane >> 4;

    f32x4 acc[8];
#pragma unroll
    for (int nt = 0; nt < 8; ++nt) acc[nt] = (f32x4){0.f, 0.f, 0.f, 0.f};

    int arow = row0 + m;
    bool avalid = arow < N;
    const s16x8* wp = (const s16x8*)Wsw;
    s16x8 az = {0, 0, 0, 0, 0, 0, 0, 0};
#pragma unroll
    for (int kt = 0; kt < 4; ++kt) {
        s16x8 a = az;
        if (avalid) {
            s16x8 raw = *(const s16x8*)&H1[(size_t)arow * D + kt * 32 + quad * 8];
#pragma unroll
            for (int j = 0; j < 8; ++j) {
                int k = kt * 32 + quad * 8 + j;
                float dd = bf2f(raw[j]) * sa[k] + sb[k];
                float o = dd / (1.f + __expf(-dd));
                a[j] = (short)f2bf(o);
            }
        }
#pragma unroll
        for (int nt = 0; nt < 8; ++nt) {
            s16x8 b = wp[(kt * 8 + nt) * 64 + lane];
            acc[nt] = __builtin_amdgcn_mfma_f32_16x16x32_bf16(a, b, acc[nt], 0, 0, 0);
        }
    }

#pragma unroll
    for (int nt = 0; nt < 8; ++nt) {
        float bv = bias[nt * 16 + m];
        float s = 0.f, q = 0.f;
#pragma unroll
        for (int r = 0; r < 4; ++r) {
            int row = row0 + quad * 4 + r;
            float h = acc[nt][r] + bv;
            if (row < N) {
                Hout[(size_t)row * D + nt * 16 + m] = f2bf(h);
                s += h; q += h * h;
            }
        }
        s += __shfl_xor(s, 16, 64); s += __shfl_xor(s, 32, 64);
        q += __shfl_xor(q, 16, 64); q += __shfl_xor(q, 32, 64);
        if (quad == 0) {
            redS[w * D + nt * 16 + m] = s;
            redQ[w * D + nt * 16 + m] = q;
        }
    }
    __syncthreads();
    if (tid < D) {
        float ts = redS[tid] + redS[D + tid] + redS[2 * D + tid] + redS[3 * D + tid];
        float tq = redQ[tid] + redQ[D + tid] + redQ[2 * D + tid] + redQ[3 * D + tid];
        atomicAdd(&stats2[tid], ts);
        atomicAdd(&stats2[D + tid], tq);
    }
}

// ---- final BN + swish -> fp32 out (finalize fused from raw sums) ----
__global__ void k_bnswish(const unsigned* __restrict__ inh, float* __restrict__ outp,
                          const float* __restrict__ stats, const float* __restrict__ g,
                          const float* __restrict__ be, float invN, int total4) {
    __shared__ float sa[D], sb[D];
    int j = threadIdx.x;
    if (j < D) {
        float mean = stats[j] * invN;
        float var = fmaxf(stats[D + j] * invN - mean * mean, 0.f);
        float a = g[j] * rsqrtf(var + 1e-5f);
        sa[j] = a;
        sb[j] = be[j] - mean * a;
    }
    __syncthreads();
    int i = blockIdx.x * blockDim.x + threadIdx.x;
    if (i >= total4) return;
    uint2 u = ((const uint2*)inh)[i];
    int c = (i * 4) & (D - 1);
    float d0 = bflo(u.x) * sa[c + 0] + sb[c + 0];
    float d1 = bfhi(u.x) * sa[c + 1] + sb[c + 1];
    float d2 = bflo(u.y) * sa[c + 2] + sb[c + 2];
    float d3 = bfhi(u.y) * sa[c + 3] + sb[c + 3];
    float o0 = d0 / (1.f + __expf(-d0));
    float o1 = d1 / (1.f + __expf(-d1));
    float o2 = d2 / (1.f + __expf(-d2));
    float o3 = d3 / (1.f + __expf(-d3));
    ((float4*)outp)[i] = make_float4(o0, o1, o2, o3);
}

extern "C" void kernel_launch(void* const* d_in, const int* in_sizes, int n_in,
                              void* d_out, int out_size, void* d_ws, size_t ws_size,
                              hipStream_t stream) {
    const float* x    = (const float*)d_in[0];
    const float* vals = (const float*)d_in[1];
    const float* W1   = (const float*)d_in[2];
    const float* b1   = (const float*)d_in[3];
    const float* g1   = (const float*)d_in[4];
    const float* be1  = (const float*)d_in[5];
    const float* W2   = (const float*)d_in[6];
    const float* b2   = (const float*)d_in[7];
    const float* g2   = (const float*)d_in[8];
    const float* be2  = (const float*)d_in[9];
    const float* eps  = (const float*)d_in[10];
    const int*  rows  = (const int*)d_in[11];
    const int*  cols  = (const int*)d_in[12];
    float* out = (float*)d_out;

    int N = in_sizes[0] / D;
    int E = in_sizes[1];
    int gblk = (N + 63) / 64;            // 782 GEMM tiles
    int npad = gblk * 64;                // 50048
    int gab = (N + GR - 1) / GR;         // 1563 gather blocks

    // ---- workspace layout ----
    char* p = (char*)d_ws;
    float* stats = (float*)p;              p += 4 * D * sizeof(float);   // stats1 | stats2
    int* rowcnt = (int*)p;                 p += (size_t)npad * sizeof(int);
    p = (char*)(((uintptr_t)p + 15) & ~(uintptr_t)15);
    unsigned short* Wsw1 = (unsigned short*)p; p += (size_t)D * D * 2;
    unsigned short* Wsw2 = (unsigned short*)p; p += (size_t)D * D * 2;
    p = (char*)(((uintptr_t)p + 15) & ~(uintptr_t)15);
    uint2* rowslab = (uint2*)p;            p += (size_t)npad * RCAP * sizeof(uint2); // 25.6 MB
    unsigned* xh = (unsigned*)p;           p += (size_t)N * DH * sizeof(unsigned);  // also H1
    unsigned* aggh = (unsigned*)p;         /* N*DH uints; also H2 */

    float* stats1 = stats;
    float* stats2 = stats + 2 * D;

    int total4 = N * D / 4;
    int eb = (total4 + 255) / 256;
    int zb = (npad + 255) / 256;
    float invN = 1.0f / (float)N;

    // 1. fused setup: xpack | prepw | zero(rowcnt,stats)
    k_setup<<<eb + 16 + zb, 256, 0, stream>>>(x, xh, total4, W1, W2, Wsw1, Wsw2,
                                              rowcnt, stats, eb, npad);
    // 2. direct per-row slab scatter
    k_scatter<<<1024, 256, 0, stream>>>(rows, cols, vals, rowcnt, rowslab, E);
    // 3. gather (slabs LDS-staged, 8 waves, 32 rows/block)
    k_gather<<<gab, 512, 0, stream>>>(rowslab, rowcnt, xh, eps, aggh, N);
    // 4. layer-1 GEMM (+stats1); H1 -> xh
    k_gemm<<<gblk, 256, 0, stream>>>((const unsigned short*)aggh, Wsw1, b1,
                                     (unsigned short*)xh, stats1, N);
    // 5. layer-2 GEMM with BN1+swish fused on A; H2 -> aggh (+stats2)
    k_gemm2f<<<gblk, 256, 0, stream>>>((const unsigned short*)xh, Wsw2, b2,
                                       stats1, g1, be1, invN,
                                       (unsigned short*)aggh, stats2, N);
    // 6. final BN+swish -> fp32 out
    k_bnswish<<<eb, 256, 0, stream>>>(aggh, out, stats2, g2, be2, invN, total4);
}

// Round 6
// 251.731 us; speedup vs baseline: 1.1030x; 1.0583x over previous
//
#include <hip/hip_runtime.h>

#define D 128
#define DH 64      // uints per feature row (2 bf16 per uint)
#define RCAP 64    // per-row slab capacity (Poisson mean 16, max over 50k rows ~35)
#define GR 32      // rows per gather block (grid ~1563 -> 4 blocks/CU sustained)
#define SB 8       // scatter batch depth (outstanding atomics per lane)

typedef float f32x4 __attribute__((ext_vector_type(4)));
typedef short s16x8 __attribute__((ext_vector_type(8)));

static __device__ __forceinline__ unsigned short f2bf(float f) {
    unsigned u = __float_as_uint(f);
    u += 0x7FFF + ((u >> 16) & 1);   // RNE
    return (unsigned short)(u >> 16);
}
static __device__ __forceinline__ float bflo(unsigned u) { return __uint_as_float(u << 16); }
static __device__ __forceinline__ float bfhi(unsigned u) { return __uint_as_float(u & 0xFFFF0000u); }
static __device__ __forceinline__ float bf2f(short v) {
    return __uint_as_float(((unsigned)(unsigned short)v) << 16);
}

// ---- fused setup: [0,eb) xpack | [eb,eb+16) prepw | [eb+16,..) zero rowcnt+stats ----
__global__ __launch_bounds__(256)
void k_setup(const float* __restrict__ x, unsigned* __restrict__ xh, int total4,
             const float* __restrict__ W1, const float* __restrict__ W2,
             unsigned short* __restrict__ Wsw1, unsigned short* __restrict__ Wsw2,
             int* __restrict__ rowcnt, float* __restrict__ stats, int eb, int npad) {
    int bid = blockIdx.x, t = threadIdx.x;
    if (bid < eb) {
        int i = bid * 256 + t;
        if (i < total4) {
            float4 v = ((const float4*)x)[i];
            uint2 o;
            o.x = (unsigned)f2bf(v.x) | ((unsigned)f2bf(v.y) << 16);
            o.y = (unsigned)f2bf(v.z) | ((unsigned)f2bf(v.w) << 16);
            ((uint2*)xh)[i] = o;
        }
    } else if (bid < eb + 16) {
        int gidx = (bid - eb) * 256 + t;   // 0..4095
        const float* W = (gidx < 2048) ? W1 : W2;
        unsigned short* Wsw = (gidx < 2048) ? Wsw1 : Wsw2;
        int idx = gidx & 2047;
        int lane = idx & 63, nt = (idx >> 6) & 7, kt = idx >> 9;
        int k0 = kt * 32 + (lane >> 4) * 8;
        int n = nt * 16 + (lane & 15);
        unsigned short* dst = &Wsw[(size_t)((kt * 8 + nt) * 64 + lane) * 8];
#pragma unroll
        for (int j = 0; j < 8; ++j) dst[j] = f2bf(W[(k0 + j) * D + n]);
    } else {
        int z = bid - eb - 16;
        int idx = z * 256 + t;
        if (idx < npad) rowcnt[idx] = 0;
        if (z == 0) { stats[t] = 0.f; stats[256 + t] = 0.f; }   // 4*D = 512 floats
    }
}

// ---- batched per-row slab scatter: 8 outstanding atomics per lane ----
// wave owns a 512-edge tile: phase1 load 8 coalesced, phase2 8 independent
// atomics, phase3 8 predicated stores. MLP 8x vs the serial R5 loop.
__global__ __launch_bounds__(256)
void k_scatter(const int* __restrict__ rows, const int* __restrict__ cols,
               const float* __restrict__ vals, int* __restrict__ rowcnt,
               uint2* __restrict__ rowslab, int E) {
    int lane = threadIdx.x & 63;
    int wid = blockIdx.x * 4 + (threadIdx.x >> 6);
    int nw = gridDim.x * 4;
    for (int base = wid * (SB * 64); base < E; base += nw * (SB * 64)) {
        int r[SB]; unsigned c[SB]; unsigned v[SB]; int p[SB];
#pragma unroll
        for (int j = 0; j < SB; ++j) {
            int e = base + j * 64 + lane;
            if (e < E) {
                r[j] = rows[e];
                c[j] = (unsigned)cols[e];
                v[j] = __float_as_uint(vals[e]);
            } else {
                r[j] = -1; c[j] = 0; v[j] = 0;
            }
        }
#pragma unroll
        for (int j = 0; j < SB; ++j)
            p[j] = (r[j] >= 0) ? atomicAdd(&rowcnt[r[j]], 1) : RCAP;
#pragma unroll
        for (int j = 0; j < SB; ++j)
            if (r[j] >= 0 && p[j] < RCAP)
                rowslab[(size_t)r[j] * RCAP + p[j]] = make_uint2(c[j], v[j]);
    }
}

// ---- gather: slabs LDS-staged (bulk coalesced), 8 waves, 32 rows/block ----
__global__ __launch_bounds__(512, 8)
void k_gather(const uint2* __restrict__ rowslab, const int* __restrict__ rowcnt,
              const unsigned* __restrict__ xh, const float* __restrict__ eps,
              unsigned* __restrict__ aggh, int N) {
    __shared__ uint2 sl[GR * RCAP];   // 16 KB staged edge slabs
    __shared__ int scnt[GR];
    int b = blockIdx.x, t = threadIdx.x;
    int row0 = b * GR;

    // bulk coalesced staging: 16 KB per block as uint4 (2 slots/op)
    {
        const uint4* src = (const uint4*)&rowslab[(size_t)row0 * RCAP];
        uint4* dst = (uint4*)sl;
        for (int i = t; i < GR * RCAP / 2; i += 512) dst[i] = src[i];
    }
    if (t < GR) {
        int g = row0 + t;
        int c = (g < N) ? rowcnt[g] : 0;
        scnt[t] = (c > RCAP) ? RCAP : c;
    }
    __syncthreads();

    int lane = t & 63, w = t >> 6;   // 8 waves, 4 rows each
    float s = 1.0f + eps[0];
    for (int rl = w; rl < GR; rl += 8) {
        int grow = row0 + rl;
        if (grow >= N) break;
        unsigned u = xh[(size_t)grow * DH + lane];
        float ax = s * bflo(u), ay = s * bfhi(u);
        int cnt = scnt[rl];
        const uint2* base = &sl[rl * RCAP];
        int i = 0;
        for (; i + 8 <= cnt; i += 8) {
            uint2 ed[8];
            unsigned uu[8];
#pragma unroll
            for (int j = 0; j < 8; ++j) ed[j] = base[i + j];
#pragma unroll
            for (int j = 0; j < 8; ++j) uu[j] = xh[(size_t)ed[j].x * DH + lane];
#pragma unroll
            for (int j = 0; j < 8; ++j) {
                float v = __uint_as_float(ed[j].y);
                ax += v * bflo(uu[j]);
                ay += v * bfhi(uu[j]);
            }
        }
        for (; i < cnt; ++i) {
            uint2 ed = base[i];
            unsigned uu = xh[(size_t)ed.x * DH + lane];
            float v = __uint_as_float(ed.y);
            ax += v * bflo(uu);
            ay += v * bfhi(uu);
        }
        aggh[(size_t)grow * DH + lane] = (unsigned)f2bf(ax) | ((unsigned)f2bf(ay) << 16);
    }
}

// ---- layer-1 MFMA GEMM + fused batch-stat partials ----
__global__ __launch_bounds__(256)
void k_gemm(const unsigned short* __restrict__ A, const unsigned short* __restrict__ Wsw,
            const float* __restrict__ bias, unsigned short* __restrict__ Hout,
            float* __restrict__ stats, int N) {
    __shared__ float redS[4 * D];
    __shared__ float redQ[4 * D];
    int tid = threadIdx.x, lane = tid & 63, w = tid >> 6;
    int row0 = blockIdx.x * 64 + w * 16;
    int m = lane & 15, quad = lane >> 4;

    f32x4 acc[8];
#pragma unroll
    for (int nt = 0; nt < 8; ++nt) acc[nt] = (f32x4){0.f, 0.f, 0.f, 0.f};

    int arow = row0 + m;
    bool avalid = arow < N;
    const s16x8* wp = (const s16x8*)Wsw;
    s16x8 az = {0, 0, 0, 0, 0, 0, 0, 0};
#pragma unroll
    for (int kt = 0; kt < 4; ++kt) {
        s16x8 a = avalid ? *(const s16x8*)&A[(size_t)arow * D + kt * 32 + quad * 8] : az;
#pragma unroll
        for (int nt = 0; nt < 8; ++nt) {
            s16x8 b = wp[(kt * 8 + nt) * 64 + lane];
            acc[nt] = __builtin_amdgcn_mfma_f32_16x16x32_bf16(a, b, acc[nt], 0, 0, 0);
        }
    }

#pragma unroll
    for (int nt = 0; nt < 8; ++nt) {
        float bv = bias[nt * 16 + m];
        float s = 0.f, q = 0.f;
#pragma unroll
        for (int r = 0; r < 4; ++r) {
            int row = row0 + quad * 4 + r;
            float h = acc[nt][r] + bv;
            if (row < N) {
                Hout[(size_t)row * D + nt * 16 + m] = f2bf(h);
                s += h; q += h * h;
            }
        }
        s += __shfl_xor(s, 16, 64); s += __shfl_xor(s, 32, 64);
        q += __shfl_xor(q, 16, 64); q += __shfl_xor(q, 32, 64);
        if (quad == 0) {
            redS[w * D + nt * 16 + m] = s;
            redQ[w * D + nt * 16 + m] = q;
        }
    }
    __syncthreads();
    if (tid < D) {
        float ts = redS[tid] + redS[D + tid] + redS[2 * D + tid] + redS[3 * D + tid];
        float tq = redQ[tid] + redQ[D + tid] + redQ[2 * D + tid] + redQ[3 * D + tid];
        atomicAdd(&stats[tid], ts);
        atomicAdd(&stats[D + tid], tq);
    }
}

// ---- layer-2 GEMM with BN1+swish fused into the A-load; stats2 partials ----
__global__ __launch_bounds__(256)
void k_gemm2f(const unsigned short* __restrict__ H1, const unsigned short* __restrict__ Wsw,
              const float* __restrict__ bias, const float* __restrict__ stats1,
              const float* __restrict__ g1, const float* __restrict__ be1, float invN,
              unsigned short* __restrict__ Hout, float* __restrict__ stats2, int N) {
    __shared__ float redS[4 * D];
    __shared__ float redQ[4 * D];
    __shared__ float sa[D], sb[D];
    int tid = threadIdx.x, lane = tid & 63, w = tid >> 6;
    if (tid < D) {
        float mean = stats1[tid] * invN;
        float var = fmaxf(stats1[D + tid] * invN - mean * mean, 0.f);
        float a = g1[tid] * rsqrtf(var + 1e-5f);
        sa[tid] = a;
        sb[tid] = be1[tid] - mean * a;
    }
    __syncthreads();

    int row0 = blockIdx.x * 64 + w * 16;
    int m = lane & 15, quad = lane >> 4;

    f32x4 acc[8];
#pragma unroll
    for (int nt = 0; nt < 8; ++nt) acc[nt] = (f32x4){0.f, 0.f, 0.f, 0.f};

    int arow = row0 + m;
    bool avalid = arow < N;
    const s16x8* wp = (const s16x8*)Wsw;
    s16x8 az = {0, 0, 0, 0, 0, 0, 0, 0};
#pragma unroll
    for (int kt = 0; kt < 4; ++kt) {
        s16x8 a = az;
        if (avalid) {
            s16x8 raw = *(const s16x8*)&H1[(size_t)arow * D + kt * 32 + quad * 8];
#pragma unroll
            for (int j = 0; j < 8; ++j) {
                int k = kt * 32 + quad * 8 + j;
                float dd = bf2f(raw[j]) * sa[k] + sb[k];
                float o = dd / (1.f + __expf(-dd));
                a[j] = (short)f2bf(o);
            }
        }
#pragma unroll
        for (int nt = 0; nt < 8; ++nt) {
            s16x8 b = wp[(kt * 8 + nt) * 64 + lane];
            acc[nt] = __builtin_amdgcn_mfma_f32_16x16x32_bf16(a, b, acc[nt], 0, 0, 0);
        }
    }

#pragma unroll
    for (int nt = 0; nt < 8; ++nt) {
        float bv = bias[nt * 16 + m];
        float s = 0.f, q = 0.f;
#pragma unroll
        for (int r = 0; r < 4; ++r) {
            int row = row0 + quad * 4 + r;
            float h = acc[nt][r] + bv;
            if (row < N) {
                Hout[(size_t)row * D + nt * 16 + m] = f2bf(h);
                s += h; q += h * h;
            }
        }
        s += __shfl_xor(s, 16, 64); s += __shfl_xor(s, 32, 64);
        q += __shfl_xor(q, 16, 64); q += __shfl_xor(q, 32, 64);
        if (quad == 0) {
            redS[w * D + nt * 16 + m] = s;
            redQ[w * D + nt * 16 + m] = q;
        }
    }
    __syncthreads();
    if (tid < D) {
        float ts = redS[tid] + redS[D + tid] + redS[2 * D + tid] + redS[3 * D + tid];
        float tq = redQ[tid] + redQ[D + tid] + redQ[2 * D + tid] + redQ[3 * D + tid];
        atomicAdd(&stats2[tid], ts);
        atomicAdd(&stats2[D + tid], tq);
    }
}

// ---- final BN + swish -> fp32 out (finalize fused from raw sums) ----
__global__ void k_bnswish(const unsigned* __restrict__ inh, float* __restrict__ outp,
                          const float* __restrict__ stats, const float* __restrict__ g,
                          const float* __restrict__ be, float invN, int total4) {
    __shared__ float sa[D], sb[D];
    int j = threadIdx.x;
    if (j < D) {
        float mean = stats[j] * invN;
        float var = fmaxf(stats[D + j] * invN - mean * mean, 0.f);
        float a = g[j] * rsqrtf(var + 1e-5f);
        sa[j] = a;
        sb[j] = be[j] - mean * a;
    }
    __syncthreads();
    int i = blockIdx.x * blockDim.x + threadIdx.x;
    if (i >= total4) return;
    uint2 u = ((const uint2*)inh)[i];
    int c = (i * 4) & (D - 1);
    float d0 = bflo(u.x) * sa[c + 0] + sb[c + 0];
    float d1 = bfhi(u.x) * sa[c + 1] + sb[c + 1];
    float d2 = bflo(u.y) * sa[c + 2] + sb[c + 2];
    float d3 = bfhi(u.y) * sa[c + 3] + sb[c + 3];
    float o0 = d0 / (1.f + __expf(-d0));
    float o1 = d1 / (1.f + __expf(-d1));
    float o2 = d2 / (1.f + __expf(-d2));
    float o3 = d3 / (1.f + __expf(-d3));
    ((float4*)outp)[i] = make_float4(o0, o1, o2, o3);
}

extern "C" void kernel_launch(void* const* d_in, const int* in_sizes, int n_in,
                              void* d_out, int out_size, void* d_ws, size_t ws_size,
                              hipStream_t stream) {
    const float* x    = (const float*)d_in[0];
    const float* vals = (const float*)d_in[1];
    const float* W1   = (const float*)d_in[2];
    const float* b1   = (const float*)d_in[3];
    const float* g1   = (const float*)d_in[4];
    const float* be1  = (const float*)d_in[5];
    const float* W2   = (const float*)d_in[6];
    const float* b2   = (const float*)d_in[7];
    const float* g2   = (const float*)d_in[8];
    const float* be2  = (const float*)d_in[9];
    const float* eps  = (const float*)d_in[10];
    const int*  rows  = (const int*)d_in[11];
    const int*  cols  = (const int*)d_in[12];
    float* out = (float*)d_out;

    int N = in_sizes[0] / D;
    int E = in_sizes[1];
    int gblk = (N + 63) / 64;            // 782 GEMM tiles
    int npad = gblk * 64;                // 50048
    int gab = (N + GR - 1) / GR;         // 1563 gather blocks

    // ---- workspace layout ----
    char* p = (char*)d_ws;
    float* stats = (float*)p;              p += 4 * D * sizeof(float);   // stats1 | stats2
    int* rowcnt = (int*)p;                 p += (size_t)npad * sizeof(int);
    p = (char*)(((uintptr_t)p + 15) & ~(uintptr_t)15);
    unsigned short* Wsw1 = (unsigned short*)p; p += (size_t)D * D * 2;
    unsigned short* Wsw2 = (unsigned short*)p; p += (size_t)D * D * 2;
    p = (char*)(((uintptr_t)p + 15) & ~(uintptr_t)15);
    uint2* rowslab = (uint2*)p;            p += (size_t)npad * RCAP * sizeof(uint2); // 25.6 MB
    unsigned* xh = (unsigned*)p;           p += (size_t)N * DH * sizeof(unsigned);  // also H1
    unsigned* aggh = (unsigned*)p;         /* N*DH uints; also H2 */

    float* stats1 = stats;
    float* stats2 = stats + 2 * D;

    int total4 = N * D / 4;
    int eb = (total4 + 255) / 256;
    int zb = (npad + 255) / 256;
    float invN = 1.0f / (float)N;
    int swaves = (E + SB * 64 - 1) / (SB * 64);   // one 512-edge tile per wave
    int sblk = (swaves + 3) / 4;                   // 391 blocks

    // 1. fused setup: xpack | prepw | zero(rowcnt,stats)
    k_setup<<<eb + 16 + zb, 256, 0, stream>>>(x, xh, total4, W1, W2, Wsw1, Wsw2,
                                              rowcnt, stats, eb, npad);
    // 2. batched per-row slab scatter (8 outstanding atomics per lane)
    k_scatter<<<sblk, 256, 0, stream>>>(rows, cols, vals, rowcnt, rowslab, E);
    // 3. gather (slabs LDS-staged, 8 waves, 32 rows/block)
    k_gather<<<gab, 512, 0, stream>>>(rowslab, rowcnt, xh, eps, aggh, N);
    // 4. layer-1 GEMM (+stats1); H1 -> xh
    k_gemm<<<gblk, 256, 0, stream>>>((const unsigned short*)aggh, Wsw1, b1,
                                     (unsigned short*)xh, stats1, N);
    // 5. layer-2 GEMM with BN1+swish fused on A; H2 -> aggh (+stats2)
    k_gemm2f<<<gblk, 256, 0, stream>>>((const unsigned short*)xh, Wsw2, b2,
                                       stats1, g1, be1, invN,
                                       (unsigned short*)aggh, stats2, N);
    // 6. final BN+swish -> fp32 out
    k_bnswish<<<eb, 256, 0, stream>>>(aggh, out, stats2, g2, be2, invN, total4);
}

// Round 7
// 221.837 us; speedup vs baseline: 1.2517x; 1.1348x over previous
//
#include <hip/hip_runtime.h>

#define D 128
#define DH 64      // uints per feature row (2 bf16 per uint)
#define BR 64      // rows per bucket (64 -> 782 buckets)
#define BSH 6      // log2(BR)
#define NBMAX 1024
#define FCAP 2048  // slab capacity per bucket (mean 1024, sigma 32)
#define GT 512     // threads in sortgather (8 waves)
#define CH 4096    // edges per scatter chunk (LDS-staged, coalesced write-out)
#define SCT 512    // scatter threads

typedef float f32x4 __attribute__((ext_vector_type(4)));
typedef short s16x8 __attribute__((ext_vector_type(8)));

static __device__ __forceinline__ unsigned short f2bf(float f) {
    unsigned u = __float_as_uint(f);
    u += 0x7FFF + ((u >> 16) & 1);   // RNE
    return (unsigned short)(u >> 16);
}
static __device__ __forceinline__ float bflo(unsigned u) { return __uint_as_float(u << 16); }
static __device__ __forceinline__ float bfhi(unsigned u) { return __uint_as_float(u & 0xFFFF0000u); }
static __device__ __forceinline__ float bf2f(short v) {
    return __uint_as_float(((unsigned)(unsigned short)v) << 16);
}

// ---- fused setup: [0,eb) xpack | [eb,eb+16) prepw | [eb+16] zero ccur+stats ----
__global__ __launch_bounds__(256)
void k_setup(const float* __restrict__ x, unsigned* __restrict__ xh, int total4,
             const float* __restrict__ W1, const float* __restrict__ W2,
             unsigned short* __restrict__ Wsw1, unsigned short* __restrict__ Wsw2,
             int* __restrict__ ccur, float* __restrict__ stats, int eb) {
    int bid = blockIdx.x, t = threadIdx.x;
    if (bid < eb) {
        int i = bid * 256 + t;
        if (i < total4) {
            float4 v = ((const float4*)x)[i];
            uint2 o;
            o.x = (unsigned)f2bf(v.x) | ((unsigned)f2bf(v.y) << 16);
            o.y = (unsigned)f2bf(v.z) | ((unsigned)f2bf(v.w) << 16);
            ((uint2*)xh)[i] = o;
        }
    } else if (bid < eb + 16) {
        int gidx = (bid - eb) * 256 + t;   // 0..4095
        const float* W = (gidx < 2048) ? W1 : W2;
        unsigned short* Wsw = (gidx < 2048) ? Wsw1 : Wsw2;
        int idx = gidx & 2047;
        int lane = idx & 63, nt = (idx >> 6) & 7, kt = idx >> 9;
        int k0 = kt * 32 + (lane >> 4) * 8;
        int n = nt * 16 + (lane & 15);
        unsigned short* dst = &Wsw[(size_t)((kt * 8 + nt) * 64 + lane) * 8];
#pragma unroll
        for (int j = 0; j < 8; ++j) dst[j] = f2bf(W[(k0 + j) * D + n]);
    } else {
        if (t < 512) stats[t] = 0.f;       // 4*D floats: stats1 | stats2
        for (int i = t; i < NBMAX; i += 256) ccur[i] = 0;
    }
}

// ---- coalesced chunk scatter: regs -> LDS bucket-sort -> grouped global writes ----
__global__ __launch_bounds__(SCT)
void k_cscatter(const int* __restrict__ rows, const int* __restrict__ cols,
                const float* __restrict__ vals, int* __restrict__ gcur,
                uint2* __restrict__ sedge, int E) {
    __shared__ int lcnt[NBMAX];
    __shared__ int lbase[NBMAX];
    __shared__ int gbase[NBMAX];
    __shared__ uint2 sl[CH];
    __shared__ unsigned short sbkt[CH];
    int t = threadIdx.x;
    int base = blockIdx.x * CH;
    int tot = min(E - base, CH);

    for (int i = t; i < NBMAX; i += SCT) lcnt[i] = 0;
    __syncthreads();

    // load 8 edges into regs + bucket count
    int r[8]; unsigned c[8], v[8];
#pragma unroll
    for (int j = 0; j < 8; ++j) {
        int e = base + j * SCT + t;
        if (e < E) {
            r[j] = rows[e];
            c[j] = (unsigned)cols[e];
            v[j] = __float_as_uint(vals[e]);
            atomicAdd(&lcnt[r[j] >> BSH], 1);
        } else r[j] = -1;
    }
    __syncthreads();

    // inclusive Hillis-Steele scan over NBMAX (512 threads x 2 slots)
    lbase[t] = lcnt[t];
    lbase[t + SCT] = lcnt[t + SCT];
    __syncthreads();
    for (int d = 1; d < NBMAX; d <<= 1) {
        int a0 = (t >= d) ? lbase[t - d] : 0;
        int i1 = t + SCT;
        int a1 = (i1 >= d) ? lbase[i1 - d] : 0;
        __syncthreads();
        lbase[t] += a0;
        lbase[i1] += a1;
        __syncthreads();
    }
    // reserve global slab space; make lbase exclusive; reset lcnt as rank counter
#pragma unroll
    for (int k = 0; k < 2; ++k) {
        int i = t + k * SCT;
        int cnt = lcnt[i];
        gbase[i] = cnt ? atomicAdd(&gcur[i], cnt) : 0;
        lbase[i] -= cnt;
    }
    __syncthreads();
    for (int i = t; i < NBMAX; i += SCT) lcnt[i] = 0;
    __syncthreads();

    // stage bucket-sorted into LDS
#pragma unroll
    for (int j = 0; j < 8; ++j) {
        if (r[j] >= 0) {
            int b = r[j] >> BSH;
            int p = lbase[b] + atomicAdd(&lcnt[b], 1);
            sl[p] = make_uint2(c[j] | ((unsigned)(r[j] & (BR - 1)) << 16), v[j]);
            sbkt[p] = (unsigned short)b;
        }
    }
    __syncthreads();

    // grouped write-out: consecutive lanes -> consecutive slab addresses
#pragma unroll
    for (int j = 0; j < 8; ++j) {
        int i = j * SCT + t;
        if (i < tot) {
            int b = sbkt[i];
            int pos = gbase[b] + (i - lbase[b]);
            if (pos < FCAP) sedge[(size_t)b * FCAP + pos] = sl[i];
        }
    }
}

// ---- fused per-bucket fine sort (LDS) + segment-sum gather ----
__global__ __launch_bounds__(GT, 8)
void k_sortgather(const uint2* __restrict__ sedge, const int* __restrict__ ccur,
                  const unsigned* __restrict__ xh, const float* __restrict__ eps,
                  unsigned* __restrict__ aggh, int N) {
    __shared__ int cnt[BR], sbase[BR], cur[BR];
    __shared__ uint2 ebufA[FCAP];   // raw staged edges
    __shared__ uint2 ebufB[FCAP];   // row-sorted edges
    int b = blockIdx.x, t = threadIdx.x;
    size_t e0 = (size_t)b * FCAP;
    int cntE = ccur[b];
    if (cntE > FCAP) cntE = FCAP;   // statistically unreachable
    if (t < BR) { cnt[t] = 0; cur[t] = 0; }
    __syncthreads();
    for (int i = t; i < cntE; i += GT) {
        uint2 ed = sedge[e0 + i];
        ebufA[i] = ed;
        atomicAdd(&cnt[ed.x >> 16], 1);
    }
    __syncthreads();
    if (t < BR) sbase[t] = cnt[t];
    __syncthreads();
    for (int d = 1; d < BR; d <<= 1) {
        int add = (t < BR && t >= d) ? sbase[t - d] : 0;
        __syncthreads();
        if (t < BR) sbase[t] += add;
        __syncthreads();
    }
    if (t < BR) sbase[t] -= cnt[t];   // exclusive prefix
    __syncthreads();
    for (int i = t; i < cntE; i += GT) {
        uint2 ed = ebufA[i];
        int r = ed.x >> 16;
        int p = sbase[r] + atomicAdd(&cur[r], 1);
        ebufB[p] = make_uint2(ed.x & 0xFFFFu, ed.y);
    }
    __syncthreads();

    // ---- gather phase ----
    int lane = t & 63, w = t >> 6;   // 8 waves
    float s = 1.0f + eps[0];
    int row0 = b * BR;
    for (int rl = w; rl < BR; rl += 8) {
        int grow = row0 + rl;
        if (grow >= N) break;
        unsigned u = xh[(size_t)grow * DH + lane];
        float ax = s * bflo(u), ay = s * bfhi(u);
        int i = sbase[rl];
        int i1 = (rl < BR - 1) ? sbase[rl + 1] : cntE;
        for (; i + 8 <= i1; i += 8) {
            uint2 ed[8];
            unsigned uu[8];
#pragma unroll
            for (int j = 0; j < 8; ++j) ed[j] = ebufB[i + j];
#pragma unroll
            for (int j = 0; j < 8; ++j) uu[j] = xh[(size_t)ed[j].x * DH + lane];
#pragma unroll
            for (int j = 0; j < 8; ++j) {
                float v = __uint_as_float(ed[j].y);
                ax += v * bflo(uu[j]);
                ay += v * bfhi(uu[j]);
            }
        }
        for (; i < i1; ++i) {
            uint2 ed = ebufB[i];
            unsigned uu = xh[(size_t)ed.x * DH + lane];
            float v = __uint_as_float(ed.y);
            ax += v * bflo(uu);
            ay += v * bfhi(uu);
        }
        aggh[(size_t)grow * DH + lane] = (unsigned)f2bf(ax) | ((unsigned)f2bf(ay) << 16);
    }
}

// ---- layer-1 MFMA GEMM + fused batch-stat partials ----
__global__ __launch_bounds__(256)
void k_gemm(const unsigned short* __restrict__ A, const unsigned short* __restrict__ Wsw,
            const float* __restrict__ bias, unsigned short* __restrict__ Hout,
            float* __restrict__ stats, int N) {
    __shared__ float redS[4 * D];
    __shared__ float redQ[4 * D];
    int tid = threadIdx.x, lane = tid & 63, w = tid >> 6;
    int row0 = blockIdx.x * 64 + w * 16;
    int m = lane & 15, quad = lane >> 4;

    f32x4 acc[8];
#pragma unroll
    for (int nt = 0; nt < 8; ++nt) acc[nt] = (f32x4){0.f, 0.f, 0.f, 0.f};

    int arow = row0 + m;
    bool avalid = arow < N;
    const s16x8* wp = (const s16x8*)Wsw;
    s16x8 az = {0, 0, 0, 0, 0, 0, 0, 0};
#pragma unroll
    for (int kt = 0; kt < 4; ++kt) {
        s16x8 a = avalid ? *(const s16x8*)&A[(size_t)arow * D + kt * 32 + quad * 8] : az;
#pragma unroll
        for (int nt = 0; nt < 8; ++nt) {
            s16x8 b = wp[(kt * 8 + nt) * 64 + lane];
            acc[nt] = __builtin_amdgcn_mfma_f32_16x16x32_bf16(a, b, acc[nt], 0, 0, 0);
        }
    }

#pragma unroll
    for (int nt = 0; nt < 8; ++nt) {
        float bv = bias[nt * 16 + m];
        float s = 0.f, q = 0.f;
#pragma unroll
        for (int r = 0; r < 4; ++r) {
            int row = row0 + quad * 4 + r;
            float h = acc[nt][r] + bv;
            if (row < N) {
                Hout[(size_t)row * D + nt * 16 + m] = f2bf(h);
                s += h; q += h * h;
            }
        }
        s += __shfl_xor(s, 16, 64); s += __shfl_xor(s, 32, 64);
        q += __shfl_xor(q, 16, 64); q += __shfl_xor(q, 32, 64);
        if (quad == 0) {
            redS[w * D + nt * 16 + m] = s;
            redQ[w * D + nt * 16 + m] = q;
        }
    }
    __syncthreads();
    if (tid < D) {
        float ts = redS[tid] + redS[D + tid] + redS[2 * D + tid] + redS[3 * D + tid];
        float tq = redQ[tid] + redQ[D + tid] + redQ[2 * D + tid] + redQ[3 * D + tid];
        atomicAdd(&stats[tid], ts);
        atomicAdd(&stats[D + tid], tq);
    }
}

// ---- layer-2 GEMM with BN1+swish fused into the A-load; stats2 partials ----
__global__ __launch_bounds__(256)
void k_gemm2f(const unsigned short* __restrict__ H1, const unsigned short* __restrict__ Wsw,
              const float* __restrict__ bias, const float* __restrict__ stats1,
              const float* __restrict__ g1, const float* __restrict__ be1, float invN,
              unsigned short* __restrict__ Hout, float* __restrict__ stats2, int N) {
    __shared__ float redS[4 * D];
    __shared__ float redQ[4 * D];
    __shared__ float sa[D], sb[D];
    int tid = threadIdx.x, lane = tid & 63, w = tid >> 6;
    if (tid < D) {
        float mean = stats1[tid] * invN;
        float var = fmaxf(stats1[D + tid] * invN - mean * mean, 0.f);
        float a = g1[tid] * rsqrtf(var + 1e-5f);
        sa[tid] = a;
        sb[tid] = be1[tid] - mean * a;
    }
    __syncthreads();

    int row0 = blockIdx.x * 64 + w * 16;
    int m = lane & 15, quad = lane >> 4;

    f32x4 acc[8];
#pragma unroll
    for (int nt = 0; nt < 8; ++nt) acc[nt] = (f32x4){0.f, 0.f, 0.f, 0.f};

    int arow = row0 + m;
    bool avalid = arow < N;
    const s16x8* wp = (const s16x8*)Wsw;
    s16x8 az = {0, 0, 0, 0, 0, 0, 0, 0};
#pragma unroll
    for (int kt = 0; kt < 4; ++kt) {
        s16x8 a = az;
        if (avalid) {
            s16x8 raw = *(const s16x8*)&H1[(size_t)arow * D + kt * 32 + quad * 8];
#pragma unroll
            for (int j = 0; j < 8; ++j) {
                int k = kt * 32 + quad * 8 + j;
                float dd = bf2f(raw[j]) * sa[k] + sb[k];
                float o = dd / (1.f + __expf(-dd));
                a[j] = (short)f2bf(o);
            }
        }
#pragma unroll
        for (int nt = 0; nt < 8; ++nt) {
            s16x8 b = wp[(kt * 8 + nt) * 64 + lane];
            acc[nt] = __builtin_amdgcn_mfma_f32_16x16x32_bf16(a, b, acc[nt], 0, 0, 0);
        }
    }

#pragma unroll
    for (int nt = 0; nt < 8; ++nt) {
        float bv = bias[nt * 16 + m];
        float s = 0.f, q = 0.f;
#pragma unroll
        for (int r = 0; r < 4; ++r) {
            int row = row0 + quad * 4 + r;
            float h = acc[nt][r] + bv;
            if (row < N) {
                Hout[(size_t)row * D + nt * 16 + m] = f2bf(h);
                s += h; q += h * h;
            }
        }
        s += __shfl_xor(s, 16, 64); s += __shfl_xor(s, 32, 64);
        q += __shfl_xor(q, 16, 64); q += __shfl_xor(q, 32, 64);
        if (quad == 0) {
            redS[w * D + nt * 16 + m] = s;
            redQ[w * D + nt * 16 + m] = q;
        }
    }
    __syncthreads();
    if (tid < D) {
        float ts = redS[tid] + redS[D + tid] + redS[2 * D + tid] + redS[3 * D + tid];
        float tq = redQ[tid] + redQ[D + tid] + redQ[2 * D + tid] + redQ[3 * D + tid];
        atomicAdd(&stats2[tid], ts);
        atomicAdd(&stats2[D + tid], tq);
    }
}

// ---- final BN + swish -> fp32 out (finalize fused from raw sums) ----
__global__ void k_bnswish(const unsigned* __restrict__ inh, float* __restrict__ outp,
                          const float* __restrict__ stats, const float* __restrict__ g,
                          const float* __restrict__ be, float invN, int total4) {
    __shared__ float sa[D], sb[D];
    int j = threadIdx.x;
    if (j < D) {
        float mean = stats[j] * invN;
        float var = fmaxf(stats[D + j] * invN - mean * mean, 0.f);
        float a = g[j] * rsqrtf(var + 1e-5f);
        sa[j] = a;
        sb[j] = be[j] - mean * a;
    }
    __syncthreads();
    int i = blockIdx.x * blockDim.x + threadIdx.x;
    if (i >= total4) return;
    uint2 u = ((const uint2*)inh)[i];
    int c = (i * 4) & (D - 1);
    float d0 = bflo(u.x) * sa[c + 0] + sb[c + 0];
    float d1 = bfhi(u.x) * sa[c + 1] + sb[c + 1];
    float d2 = bflo(u.y) * sa[c + 2] + sb[c + 2];
    float d3 = bfhi(u.y) * sa[c + 3] + sb[c + 3];
    float o0 = d0 / (1.f + __expf(-d0));
    float o1 = d1 / (1.f + __expf(-d1));
    float o2 = d2 / (1.f + __expf(-d2));
    float o3 = d3 / (1.f + __expf(-d3));
    ((float4*)outp)[i] = make_float4(o0, o1, o2, o3);
}

extern "C" void kernel_launch(void* const* d_in, const int* in_sizes, int n_in,
                              void* d_out, int out_size, void* d_ws, size_t ws_size,
                              hipStream_t stream) {
    const float* x    = (const float*)d_in[0];
    const float* vals = (const float*)d_in[1];
    const float* W1   = (const float*)d_in[2];
    const float* b1   = (const float*)d_in[3];
    const float* g1   = (const float*)d_in[4];
    const float* be1  = (const float*)d_in[5];
    const float* W2   = (const float*)d_in[6];
    const float* b2   = (const float*)d_in[7];
    const float* g2   = (const float*)d_in[8];
    const float* be2  = (const float*)d_in[9];
    const float* eps  = (const float*)d_in[10];
    const int*  rows  = (const int*)d_in[11];
    const int*  cols  = (const int*)d_in[12];
    float* out = (float*)d_out;

    int N = in_sizes[0] / D;
    int E = in_sizes[1];
    int nb = (N + BR - 1) / BR;          // 782 buckets

    // ---- workspace layout ----
    char* p = (char*)d_ws;
    float* stats = (float*)p;              p += 4 * D * sizeof(float);   // stats1 | stats2
    int* ccur = (int*)p;                   p += (size_t)NBMAX * sizeof(int);
    p = (char*)(((uintptr_t)p + 15) & ~(uintptr_t)15);
    unsigned short* Wsw1 = (unsigned short*)p; p += (size_t)D * D * 2;
    unsigned short* Wsw2 = (unsigned short*)p; p += (size_t)D * D * 2;
    p = (char*)(((uintptr_t)p + 15) & ~(uintptr_t)15);
    uint2* sedge  = (uint2*)p;             p += (size_t)nb * FCAP * sizeof(uint2);  // slabs
    unsigned* xh = (unsigned*)p;           p += (size_t)N * DH * sizeof(unsigned);  // also H1
    unsigned* aggh = (unsigned*)p;         /* N*DH uints; also H2 */

    float* stats1 = stats;
    float* stats2 = stats + 2 * D;

    int total4 = N * D / 4;
    int eb = (total4 + 255) / 256;
    int gblk = (N + 63) / 64;
    float invN = 1.0f / (float)N;
    int scb = (E + CH - 1) / CH;           // 196 scatter chunks

    // 1. fused setup: xpack | prepw | zero(ccur,stats)
    k_setup<<<eb + 17, 256, 0, stream>>>(x, xh, total4, W1, W2, Wsw1, Wsw2,
                                         ccur, stats, eb);
    // 2. coalesced chunk scatter (LDS bucket-sort, grouped writes)
    k_cscatter<<<scb, SCT, 0, stream>>>(rows, cols, vals, ccur, sedge, E);
    // 3. fused fine sort + gather
    k_sortgather<<<nb, GT, 0, stream>>>(sedge, ccur, xh, eps, aggh, N);
    // 4. layer-1 GEMM (+stats1); H1 -> xh
    k_gemm<<<gblk, 256, 0, stream>>>((const unsigned short*)aggh, Wsw1, b1,
                                     (unsigned short*)xh, stats1, N);
    // 5. layer-2 GEMM with BN1+swish fused on A; H2 -> aggh (+stats2)
    k_gemm2f<<<gblk, 256, 0, stream>>>((const unsigned short*)xh, Wsw2, b2,
                                       stats1, g1, be1, invN,
                                       (unsigned short*)aggh, stats2, N);
    // 6. final BN+swish -> fp32 out
    k_bnswish<<<eb, 256, 0, stream>>>(aggh, out, stats2, g2, be2, invN, total4);
}

// Round 8
// 207.611 us; speedup vs baseline: 1.3374x; 1.0685x over previous
//
#include <hip/hip_runtime.h>

#define D 128
#define DH 64      // uints per feature row (2 bf16 per uint)
#define BR 64      // rows per bucket (64 -> 782 buckets)
#define BSH 6      // log2(BR)
#define NBMAX 1024
#define FCAP 2048  // slab capacity per bucket (mean 1024, sigma 32)
#define GT 512     // threads in sortgathergemm (8 waves)
#define CH 4096    // edges per scatter chunk (LDS-staged, coalesced write-out)
#define SCT 512    // scatter threads
#define TS 68      // LDS agg-tile row stride in uints (272 B, 16B-aligned, bank-spread)

typedef float f32x4 __attribute__((ext_vector_type(4)));
typedef short s16x8 __attribute__((ext_vector_type(8)));

static __device__ __forceinline__ unsigned short f2bf(float f) {
    unsigned u = __float_as_uint(f);
    u += 0x7FFF + ((u >> 16) & 1);   // RNE
    return (unsigned short)(u >> 16);
}
static __device__ __forceinline__ float bflo(unsigned u) { return __uint_as_float(u << 16); }
static __device__ __forceinline__ float bfhi(unsigned u) { return __uint_as_float(u & 0xFFFF0000u); }
static __device__ __forceinline__ float bf2f(short v) {
    return __uint_as_float(((unsigned)(unsigned short)v) << 16);
}

// ---- fused setup: [0,eb) xpack | [eb,eb+16) prepw | [eb+16] zero ccur+stats ----
__global__ __launch_bounds__(256)
void k_setup(const float* __restrict__ x, unsigned* __restrict__ xh, int total4,
             const float* __restrict__ W1, const float* __restrict__ W2,
             unsigned short* __restrict__ Wsw1, unsigned short* __restrict__ Wsw2,
             int* __restrict__ ccur, float* __restrict__ stats, int eb) {
    int bid = blockIdx.x, t = threadIdx.x;
    if (bid < eb) {
        int i = bid * 256 + t;
        if (i < total4) {
            float4 v = ((const float4*)x)[i];
            uint2 o;
            o.x = (unsigned)f2bf(v.x) | ((unsigned)f2bf(v.y) << 16);
            o.y = (unsigned)f2bf(v.z) | ((unsigned)f2bf(v.w) << 16);
            ((uint2*)xh)[i] = o;
        }
    } else if (bid < eb + 16) {
        int gidx = (bid - eb) * 256 + t;   // 0..4095
        const float* W = (gidx < 2048) ? W1 : W2;
        unsigned short* Wsw = (gidx < 2048) ? Wsw1 : Wsw2;
        int idx = gidx & 2047;
        int lane = idx & 63, nt = (idx >> 6) & 7, kt = idx >> 9;
        int k0 = kt * 32 + (lane >> 4) * 8;
        int n = nt * 16 + (lane & 15);
        unsigned short* dst = &Wsw[(size_t)((kt * 8 + nt) * 64 + lane) * 8];
#pragma unroll
        for (int j = 0; j < 8; ++j) dst[j] = f2bf(W[(k0 + j) * D + n]);
    } else {
        if (t < 512) stats[t] = 0.f;       // 4*D floats: stats1 | stats2
        for (int i = t; i < NBMAX; i += 256) ccur[i] = 0;
    }
}

// ---- coalesced chunk scatter: regs -> LDS bucket-sort -> grouped global writes ----
__global__ __launch_bounds__(SCT)
void k_cscatter(const int* __restrict__ rows, const int* __restrict__ cols,
                const float* __restrict__ vals, int* __restrict__ gcur,
                uint2* __restrict__ sedge, int E) {
    __shared__ int lcnt[NBMAX];
    __shared__ int lbase[NBMAX];
    __shared__ int gbase[NBMAX];
    __shared__ uint2 sl[CH];
    __shared__ unsigned short sbkt[CH];
    int t = threadIdx.x;
    int base = blockIdx.x * CH;
    int tot = min(E - base, CH);

    for (int i = t; i < NBMAX; i += SCT) lcnt[i] = 0;
    __syncthreads();

    // load 8 edges into regs + bucket count
    int r[8]; unsigned c[8], v[8];
#pragma unroll
    for (int j = 0; j < 8; ++j) {
        int e = base + j * SCT + t;
        if (e < E) {
            r[j] = rows[e];
            c[j] = (unsigned)cols[e];
            v[j] = __float_as_uint(vals[e]);
            atomicAdd(&lcnt[r[j] >> BSH], 1);
        } else r[j] = -1;
    }
    __syncthreads();

    // inclusive Hillis-Steele scan over NBMAX (512 threads x 2 slots)
    lbase[t] = lcnt[t];
    lbase[t + SCT] = lcnt[t + SCT];
    __syncthreads();
    for (int d = 1; d < NBMAX; d <<= 1) {
        int a0 = (t >= d) ? lbase[t - d] : 0;
        int i1 = t + SCT;
        int a1 = (i1 >= d) ? lbase[i1 - d] : 0;
        __syncthreads();
        lbase[t] += a0;
        lbase[i1] += a1;
        __syncthreads();
    }
    // reserve global slab space; make lbase exclusive; reset lcnt as rank counter
#pragma unroll
    for (int k = 0; k < 2; ++k) {
        int i = t + k * SCT;
        int cnt = lcnt[i];
        gbase[i] = cnt ? atomicAdd(&gcur[i], cnt) : 0;
        lbase[i] -= cnt;
    }
    __syncthreads();
    for (int i = t; i < NBMAX; i += SCT) lcnt[i] = 0;
    __syncthreads();

    // stage bucket-sorted into LDS
#pragma unroll
    for (int j = 0; j < 8; ++j) {
        if (r[j] >= 0) {
            int b = r[j] >> BSH;
            int p = lbase[b] + atomicAdd(&lcnt[b], 1);
            sl[p] = make_uint2(c[j] | ((unsigned)(r[j] & (BR - 1)) << 16), v[j]);
            sbkt[p] = (unsigned short)b;
        }
    }
    __syncthreads();

    // grouped write-out: consecutive lanes -> consecutive slab addresses
#pragma unroll
    for (int j = 0; j < 8; ++j) {
        int i = j * SCT + t;
        if (i < tot) {
            int b = sbkt[i];
            int pos = gbase[b] + (i - lbase[b]);
            if (pos < FCAP) sedge[(size_t)b * FCAP + pos] = sl[i];
        }
    }
}

// ---- fused: per-bucket fine sort (LDS) + gather -> LDS tile + layer-1 GEMM ----
// 512 thr = 8 waves. Gather: wave w owns rows w, w+8, ... GEMM1: wave w owns
// a 16x64 output sub-tile (rows (w&3)*16, cols (w>>2)*64).
__global__ __launch_bounds__(GT, 8)
void k_sgg(const uint2* __restrict__ sedge, const int* __restrict__ ccur,
           const unsigned* __restrict__ xh, const float* __restrict__ eps,
           const unsigned short* __restrict__ Wsw, const float* __restrict__ bias,
           unsigned short* __restrict__ Hout, float* __restrict__ stats, int N) {
    __shared__ int cnt[BR], sbase[BR], cur[BR];
    __shared__ __align__(16) unsigned char uAbuf[64 * TS * 4];  // ebufA (16K) / tile (17K)
    __shared__ uint2 ebufB[FCAP];   // row-sorted edges (16 KB)
    __shared__ float redS[8 * 64];
    __shared__ float redQ[8 * 64];
    uint2* ebufA = (uint2*)uAbuf;
    unsigned* tile = (unsigned*)uAbuf;

    int b = blockIdx.x, t = threadIdx.x;
    size_t e0 = (size_t)b * FCAP;
    int cntE = ccur[b];
    if (cntE > FCAP) cntE = FCAP;   // statistically unreachable
    if (t < BR) { cnt[t] = 0; cur[t] = 0; }
    __syncthreads();
    for (int i = t; i < cntE; i += GT) {
        uint2 ed = sedge[e0 + i];
        ebufA[i] = ed;
        atomicAdd(&cnt[ed.x >> 16], 1);
    }
    __syncthreads();
    if (t < BR) sbase[t] = cnt[t];
    __syncthreads();
    for (int d = 1; d < BR; d <<= 1) {
        int add = (t < BR && t >= d) ? sbase[t - d] : 0;
        __syncthreads();
        if (t < BR) sbase[t] += add;
        __syncthreads();
    }
    if (t < BR) sbase[t] -= cnt[t];   // exclusive prefix
    __syncthreads();
    for (int i = t; i < cntE; i += GT) {
        uint2 ed = ebufA[i];
        int r = ed.x >> 16;
        int p = sbase[r] + atomicAdd(&cur[r], 1);
        ebufB[p] = make_uint2(ed.x & 0xFFFFu, ed.y);
    }
    __syncthreads();   // ebufA dead from here; tile aliases it

    // ---- gather phase: result -> LDS tile (row rl, uint lane) ----
    int lane = t & 63, w = t >> 6;   // 8 waves
    float s = 1.0f + eps[0];
    int row0 = b * BR;
    for (int rl = w; rl < BR; rl += 8) {
        int grow = row0 + rl;
        if (grow >= N) { tile[rl * TS + lane] = 0; continue; }
        unsigned u = xh[(size_t)grow * DH + lane];
        float ax = s * bflo(u), ay = s * bfhi(u);
        int i = sbase[rl];
        int i1 = (rl < BR - 1) ? sbase[rl + 1] : cntE;
        for (; i + 8 <= i1; i += 8) {
            uint2 ed[8];
            unsigned uu[8];
#pragma unroll
            for (int j = 0; j < 8; ++j) ed[j] = ebufB[i + j];
#pragma unroll
            for (int j = 0; j < 8; ++j) uu[j] = xh[(size_t)ed[j].x * DH + lane];
#pragma unroll
            for (int j = 0; j < 8; ++j) {
                float v = __uint_as_float(ed[j].y);
                ax += v * bflo(uu[j]);
                ay += v * bfhi(uu[j]);
            }
        }
        for (; i < i1; ++i) {
            uint2 ed = ebufB[i];
            unsigned uu = xh[(size_t)ed.x * DH + lane];
            float v = __uint_as_float(ed.y);
            ax += v * bflo(uu);
            ay += v * bfhi(uu);
        }
        tile[rl * TS + lane] = (unsigned)f2bf(ax) | ((unsigned)f2bf(ay) << 16);
    }
    __syncthreads();

    // ---- GEMM1 phase: wave w -> rows (w&3)*16..+16, cols (w>>2)*64..+64 ----
    int m = lane & 15, quad = lane >> 4;
    int wr = w & 3, wc = w >> 2;
    int arowl = wr * 16 + m;

    f32x4 acc[4];
#pragma unroll
    for (int ntl = 0; ntl < 4; ++ntl) acc[ntl] = (f32x4){0.f, 0.f, 0.f, 0.f};

    const s16x8* wp = (const s16x8*)Wsw;
#pragma unroll
    for (int kt = 0; kt < 4; ++kt) {
        s16x8 a = *(const s16x8*)&tile[arowl * TS + kt * 16 + quad * 4];
#pragma unroll
        for (int ntl = 0; ntl < 4; ++ntl) {
            int nt = wc * 4 + ntl;
            s16x8 bf = wp[(kt * 8 + nt) * 64 + lane];
            acc[ntl] = __builtin_amdgcn_mfma_f32_16x16x32_bf16(a, bf, acc[ntl], 0, 0, 0);
        }
    }

#pragma unroll
    for (int ntl = 0; ntl < 4; ++ntl) {
        int nt = wc * 4 + ntl;
        float bv = bias[nt * 16 + m];
        float ss = 0.f, q = 0.f;
#pragma unroll
        for (int r = 0; r < 4; ++r) {
            int row = row0 + wr * 16 + quad * 4 + r;
            float h = acc[ntl][r] + bv;
            if (row < N) {
                Hout[(size_t)row * D + nt * 16 + m] = f2bf(h);
                ss += h; q += h * h;
            }
        }
        ss += __shfl_xor(ss, 16, 64); ss += __shfl_xor(ss, 32, 64);
        q += __shfl_xor(q, 16, 64);   q += __shfl_xor(q, 32, 64);
        if (quad == 0) {
            redS[w * 64 + ntl * 16 + m] = ss;
            redQ[w * 64 + ntl * 16 + m] = q;
        }
    }
    __syncthreads();
    if (t < D) {
        int ch = t >> 6, cl = t & 63;
        float ts = 0.f, tq = 0.f;
#pragma unroll
        for (int wr2 = 0; wr2 < 4; ++wr2) {
            ts += redS[(ch * 4 + wr2) * 64 + cl];
            tq += redQ[(ch * 4 + wr2) * 64 + cl];
        }
        atomicAdd(&stats[t], ts);
        atomicAdd(&stats[D + t], tq);
    }
}

// ---- layer-2 GEMM with BN1+swish fused into the A-load; stats2 partials ----
__global__ __launch_bounds__(256)
void k_gemm2f(const unsigned short* __restrict__ H1, const unsigned short* __restrict__ Wsw,
              const float* __restrict__ bias, const float* __restrict__ stats1,
              const float* __restrict__ g1, const float* __restrict__ be1, float invN,
              unsigned short* __restrict__ Hout, float* __restrict__ stats2, int N) {
    __shared__ float redS[4 * D];
    __shared__ float redQ[4 * D];
    __shared__ float sa[D], sb[D];
    int tid = threadIdx.x, lane = tid & 63, w = tid >> 6;
    if (tid < D) {
        float mean = stats1[tid] * invN;
        float var = fmaxf(stats1[D + tid] * invN - mean * mean, 0.f);
        float a = g1[tid] * rsqrtf(var + 1e-5f);
        sa[tid] = a;
        sb[tid] = be1[tid] - mean * a;
    }
    __syncthreads();

    int row0 = blockIdx.x * 64 + w * 16;
    int m = lane & 15, quad = lane >> 4;

    f32x4 acc[8];
#pragma unroll
    for (int nt = 0; nt < 8; ++nt) acc[nt] = (f32x4){0.f, 0.f, 0.f, 0.f};

    int arow = row0 + m;
    bool avalid = arow < N;
    const s16x8* wp = (const s16x8*)Wsw;
    s16x8 az = {0, 0, 0, 0, 0, 0, 0, 0};
#pragma unroll
    for (int kt = 0; kt < 4; ++kt) {
        s16x8 a = az;
        if (avalid) {
            s16x8 raw = *(const s16x8*)&H1[(size_t)arow * D + kt * 32 + quad * 8];
#pragma unroll
            for (int j = 0; j < 8; ++j) {
                int k = kt * 32 + quad * 8 + j;
                float dd = bf2f(raw[j]) * sa[k] + sb[k];
                float o = dd / (1.f + __expf(-dd));
                a[j] = (short)f2bf(o);
            }
        }
#pragma unroll
        for (int nt = 0; nt < 8; ++nt) {
            s16x8 b = wp[(kt * 8 + nt) * 64 + lane];
            acc[nt] = __builtin_amdgcn_mfma_f32_16x16x32_bf16(a, b, acc[nt], 0, 0, 0);
        }
    }

#pragma unroll
    for (int nt = 0; nt < 8; ++nt) {
        float bv = bias[nt * 16 + m];
        float s = 0.f, q = 0.f;
#pragma unroll
        for (int r = 0; r < 4; ++r) {
            int row = row0 + quad * 4 + r;
            float h = acc[nt][r] + bv;
            if (row < N) {
                Hout[(size_t)row * D + nt * 16 + m] = f2bf(h);
                s += h; q += h * h;
            }
        }
        s += __shfl_xor(s, 16, 64); s += __shfl_xor(s, 32, 64);
        q += __shfl_xor(q, 16, 64); q += __shfl_xor(q, 32, 64);
        if (quad == 0) {
            redS[w * D + nt * 16 + m] = s;
            redQ[w * D + nt * 16 + m] = q;
        }
    }
    __syncthreads();
    if (tid < D) {
        float ts = redS[tid] + redS[D + tid] + redS[2 * D + tid] + redS[3 * D + tid];
        float tq = redQ[tid] + redQ[D + tid] + redQ[2 * D + tid] + redQ[3 * D + tid];
        atomicAdd(&stats2[tid], ts);
        atomicAdd(&stats2[D + tid], tq);
    }
}

// ---- final BN + swish -> fp32 out (finalize fused from raw sums) ----
__global__ void k_bnswish(const unsigned* __restrict__ inh, float* __restrict__ outp,
                          const float* __restrict__ stats, const float* __restrict__ g,
                          const float* __restrict__ be, float invN, int total4) {
    __shared__ float sa[D], sb[D];
    int j = threadIdx.x;
    if (j < D) {
        float mean = stats[j] * invN;
        float var = fmaxf(stats[D + j] * invN - mean * mean, 0.f);
        float a = g[j] * rsqrtf(var + 1e-5f);
        sa[j] = a;
        sb[j] = be[j] - mean * a;
    }
    __syncthreads();
    int i = blockIdx.x * blockDim.x + threadIdx.x;
    if (i >= total4) return;
    uint2 u = ((const uint2*)inh)[i];
    int c = (i * 4) & (D - 1);
    float d0 = bflo(u.x) * sa[c + 0] + sb[c + 0];
    float d1 = bfhi(u.x) * sa[c + 1] + sb[c + 1];
    float d2 = bflo(u.y) * sa[c + 2] + sb[c + 2];
    float d3 = bfhi(u.y) * sa[c + 3] + sb[c + 3];
    float o0 = d0 / (1.f + __expf(-d0));
    float o1 = d1 / (1.f + __expf(-d1));
    float o2 = d2 / (1.f + __expf(-d2));
    float o3 = d3 / (1.f + __expf(-d3));
    ((float4*)outp)[i] = make_float4(o0, o1, o2, o3);
}

extern "C" void kernel_launch(void* const* d_in, const int* in_sizes, int n_in,
                              void* d_out, int out_size, void* d_ws, size_t ws_size,
                              hipStream_t stream) {
    const float* x    = (const float*)d_in[0];
    const float* vals = (const float*)d_in[1];
    const float* W1   = (const float*)d_in[2];
    const float* b1   = (const float*)d_in[3];
    const float* g1   = (const float*)d_in[4];
    const float* be1  = (const float*)d_in[5];
    const float* W2   = (const float*)d_in[6];
    const float* b2   = (const float*)d_in[7];
    const float* g2   = (const float*)d_in[8];
    const float* be2  = (const float*)d_in[9];
    const float* eps  = (const float*)d_in[10];
    const int*  rows  = (const int*)d_in[11];
    const int*  cols  = (const int*)d_in[12];
    float* out = (float*)d_out;

    int N = in_sizes[0] / D;
    int E = in_sizes[1];
    int nb = (N + BR - 1) / BR;          // 782 buckets

    // ---- workspace layout ----
    char* p = (char*)d_ws;
    float* stats = (float*)p;              p += 4 * D * sizeof(float);   // stats1 | stats2
    int* ccur = (int*)p;                   p += (size_t)NBMAX * sizeof(int);
    p = (char*)(((uintptr_t)p + 15) & ~(uintptr_t)15);
    unsigned short* Wsw1 = (unsigned short*)p; p += (size_t)D * D * 2;
    unsigned short* Wsw2 = (unsigned short*)p; p += (size_t)D * D * 2;
    p = (char*)(((uintptr_t)p + 15) & ~(uintptr_t)15);
    uint2* sedge  = (uint2*)p;             p += (size_t)nb * FCAP * sizeof(uint2);  // slabs
    unsigned* xh = (unsigned*)p;           p += (size_t)N * DH * sizeof(unsigned);
    unsigned* h1 = (unsigned*)p;           /* N*DH uints; H2 reuses xh */

    float* stats1 = stats;
    float* stats2 = stats + 2 * D;

    int total4 = N * D / 4;
    int eb = (total4 + 255) / 256;
    int gblk = (N + 63) / 64;
    float invN = 1.0f / (float)N;
    int scb = (E + CH - 1) / CH;           // 196 scatter chunks

    // 1. fused setup: xpack | prepw | zero(ccur,stats)
    k_setup<<<eb + 17, 256, 0, stream>>>(x, xh, total4, W1, W2, Wsw1, Wsw2,
                                         ccur, stats, eb);
    // 2. coalesced chunk scatter (LDS bucket-sort, grouped writes)
    k_cscatter<<<scb, SCT, 0, stream>>>(rows, cols, vals, ccur, sedge, E);
    // 3. fused fine sort + gather + layer-1 GEMM (+stats1); H1 -> h1
    k_sgg<<<nb, GT, 0, stream>>>(sedge, ccur, xh, eps, Wsw1, b1,
                                 (unsigned short*)h1, stats1, N);
    // 4. layer-2 GEMM with BN1+swish fused on A; H2 -> xh (+stats2)
    k_gemm2f<<<gblk, 256, 0, stream>>>((const unsigned short*)h1, Wsw2, b2,
                                       stats1, g1, be1, invN,
                                       (unsigned short*)xh, stats2, N);
    // 5. final BN+swish -> fp32 out
    k_bnswish<<<eb, 256, 0, stream>>>(xh, out, stats2, g2, be2, invN, total4);
}